// Round 5
// baseline (777.331 us; speedup 1.0000x reference)
//
#include <hip/hip_runtime.h>
#include <hip/hip_bf16.h>

typedef __hip_bfloat16 bf16;
typedef __attribute__((ext_vector_type(8))) short bf16x8;
typedef __attribute__((ext_vector_type(4))) short bf16x4v;
typedef __attribute__((ext_vector_type(4))) float f32x4;

__device__ __forceinline__ void gload_lds16(const void* g, void* l)
{
    __builtin_amdgcn_global_load_lds(
        (const __attribute__((address_space(1))) void*)g,
        (__attribute__((address_space(3))) void*)l, 16, 0, 0);
}

__device__ __forceinline__ float silu_f(float v) { return v / (1.f + expf(-v)); }

__device__ __forceinline__ void st4b(bf16* p, float a, float b, float c, float d)
{
    bf16 t[4] = {__float2bfloat16(a), __float2bfloat16(b),
                 __float2bfloat16(c), __float2bfloat16(d)};
    *(bf16x4v*)p = *(const bf16x4v*)t;
}

// ---------------------------------------------------------------------------
// MFMA bf16 GEMM: C = epi(A @ Bt^T + bias), K % 64 == 0.
// BK=64 single-buffered, XOR-swizzled LDS (conflict-free, round-3 proven).
// ---------------------------------------------------------------------------
template<typename TA, typename TC, int EPI>
__global__ __launch_bounds__(256) void mgemm(
    const TA* __restrict__ A, const bf16* __restrict__ Bt,
    const float* __restrict__ bias, const float* __restrict__ rowscale,
    TC* __restrict__ C, int M, int K, int N, int ka)
{
    __shared__ __align__(16) bf16 As[128 * 64];
    __shared__ __align__(16) bf16 Bs[128 * 64];
    const int tid = threadIdx.x;
    const int lane = tid & 63;
    const int wave = tid >> 6;
    const int col16 = lane & 15;
    const int quad = lane >> 4;
    const int wm = (wave & 1) * 64;
    const int wn = (wave >> 1) * 64;
    const size_t m0 = (size_t)blockIdx.x * 128;
    const int n0 = blockIdx.y * 128;

    f32x4 acc[4][4];
#pragma unroll
    for (int i = 0; i < 4; ++i)
#pragma unroll
        for (int j = 0; j < 4; ++j) acc[i][j] = (f32x4){0.f, 0.f, 0.f, 0.f};

    const int rloc = lane >> 3;      // row within 8-row gload group
    const int gpos = lane & 7;       // granule position within row

    for (int kc = 0; kc < K; kc += 64) {
        // ---- stage A ----
        if constexpr (sizeof(TA) == 2) {
#pragma unroll
            for (int i = 0; i < 4; ++i) {
                int row = wave * 32 + i * 8 + rloc;
                int gs = gpos ^ (row & 7);
                gload_lds16((const bf16*)A + (m0 + row) * (size_t)K + kc + gs * 8,
                            As + (wave * 32 + i * 8) * 64);
            }
        } else {
#pragma unroll
            for (int r = 0; r < 4; ++r) {
                int slot = tid + 256 * r;         // 0..1023
                int row = slot >> 3;              // 0..127
                int gl = slot & 7;                // logical granule
                int gp = gl ^ (row & 7);          // phys granule
                int kg = kc + gl * 8;
                const float* ap = (const float*)A + (m0 + row) * (size_t)ka + kg;
                float4 v0 = make_float4(0.f, 0.f, 0.f, 0.f), v1 = v0;
                if (kg < ka) v0 = *(const float4*)ap;
                if (kg + 4 < ka) v1 = *(const float4*)(ap + 4);
                bf16 t[8] = {__float2bfloat16(v0.x), __float2bfloat16(v0.y),
                             __float2bfloat16(v0.z), __float2bfloat16(v0.w),
                             __float2bfloat16(v1.x), __float2bfloat16(v1.y),
                             __float2bfloat16(v1.z), __float2bfloat16(v1.w)};
                *(bf16x8*)(As + row * 64 + gp * 8) = *(const bf16x8*)t;
            }
        }
        // ---- stage B ----
#pragma unroll
        for (int i = 0; i < 4; ++i) {
            int row = wave * 32 + i * 8 + rloc;
            int gs = gpos ^ (row & 7);
            gload_lds16(Bt + (size_t)(n0 + row) * K + kc + gs * 8,
                        Bs + (wave * 32 + i * 8) * 64);
        }
        __syncthreads();

#pragma unroll
        for (int s = 0; s < 2; ++s) {
            bf16x8 a[4], b[4];
#pragma unroll
            for (int i = 0; i < 4; ++i) {
                int row = wm + i * 16 + col16;
                a[i] = *(const bf16x8*)(As + row * 64 + ((s * 4 + quad) ^ (row & 7)) * 8);
            }
#pragma unroll
            for (int j = 0; j < 4; ++j) {
                int row = wn + j * 16 + col16;
                b[j] = *(const bf16x8*)(Bs + row * 64 + ((s * 4 + quad) ^ (row & 7)) * 8);
            }
#pragma unroll
            for (int i = 0; i < 4; ++i)
#pragma unroll
                for (int j = 0; j < 4; ++j)
                    acc[i][j] = __builtin_amdgcn_mfma_f32_16x16x32_bf16(a[i], b[j], acc[i][j], 0, 0, 0);
        }
        __syncthreads();
    }

#pragma unroll
    for (int j = 0; j < 4; ++j) {
        int col = n0 + wn + j * 16 + col16;
        float bv = bias ? bias[col] : 0.f;
#pragma unroll
        for (int i = 0; i < 4; ++i) {
#pragma unroll
            for (int r = 0; r < 4; ++r) {
                size_t row = m0 + wm + i * 16 + quad * 4 + r;
                float v = acc[i][j][r] + bv;
                if (EPI == 1) v = silu_f(v);
                if (EPI == 2) v *= rowscale[row];
                if constexpr (sizeof(TC) == 2)
                    ((bf16*)C)[row * (size_t)N + col] = __float2bfloat16(v);
                else
                    ((float*)C)[row * (size_t)N + col] = v;
            }
        }
    }
}

// ---------------------------------------------------------------------------
// Fused filter pipeline v5, one 128-edge-slot block:
//   GEMM1 swapped (accT = h^T) -> Hs[edge][hcol] via 8B swizzled LDS stores
//   GEMM2 STANDARD orientation -> filc via round-3's column-contiguous stores
//     (round-4 lesson: row-scattered 8B global stores caused HBM RMW,
//      FETCH +114MB / WRITE +78MB)
// W1/W2 read as FRAGMENT-MAJOR from global (cvt_frag layout): each fragment
// load is a fully-coalesced 1KB instruction, L2-resident. No weight LDS.
// LDS 40KB -> 4 blocks/CU, 2 barriers total.
// ---------------------------------------------------------------------------
__global__ __launch_bounds__(256, 4) void fil_fused(
    const float* __restrict__ rbf, const bf16* __restrict__ W1f,
    const float* __restrict__ b1, const bf16* __restrict__ W2f,
    const float* __restrict__ b2, const float* __restrict__ cutp,
    const int* __restrict__ perm, bf16* __restrict__ filc, unsigned apmask)
{
    __shared__ __align__(16) bf16 Ar[128 * 32];   // 8 KB
    __shared__ __align__(16) bf16 Hs[128 * 128];  // 32 KB
    const int tid = threadIdx.x;
    const int lane = tid & 63;
    const int wave = tid >> 6;
    const int col16 = lane & 15;
    const int quad = lane >> 4;
    const int we = (wave & 1) * 64;    // edge offset (GEMM1)
    const int wh = (wave >> 1) * 64;   // hcol offset (GEMM1)
    const int m0 = blockIdx.x * 128;

    // ---- stage Ar: rbf gather f32->bf16, 4 granules/row, swz (row&3) ----
#pragma unroll
    for (int r = 0; r < 2; ++r) {
        int slot = tid + 256 * r;       // 0..511
        int row = slot >> 2;
        int gl = slot & 3;
        int gp = gl ^ (row & 3);
        size_t arow = (size_t)(unsigned)(perm[m0 + row] & (int)apmask);
        int kg = gl * 8;
        const float* ap = rbf + arow * 20 + kg;
        float4 v0 = make_float4(0.f, 0.f, 0.f, 0.f), v1 = v0;
        if (kg < 20) v0 = *(const float4*)ap;
        if (kg + 4 < 20) v1 = *(const float4*)(ap + 4);
        bf16 t[8] = {__float2bfloat16(v0.x), __float2bfloat16(v0.y),
                     __float2bfloat16(v0.z), __float2bfloat16(v0.w),
                     __float2bfloat16(v1.x), __float2bfloat16(v1.y),
                     __float2bfloat16(v1.z), __float2bfloat16(v1.w)};
        *(bf16x8*)(Ar + row * 32 + gp * 8) = *(const bf16x8*)t;
    }
    // W1 fragments, fragment-major coalesced: hb = (wave>>1)*4 + j
    bf16x8 w1f[4];
#pragma unroll
    for (int j = 0; j < 4; ++j)
        w1f[j] = *(const bf16x8*)(W1f + (size_t)(((wave >> 1) * 4 + j) * 64 + lane) * 8);
    __syncthreads();

    // ---- GEMM1 swapped: accT[j][i] = h^T tile [hcol][edge] ----
    f32x4 accT[4][4];
#pragma unroll
    for (int j = 0; j < 4; ++j)
#pragma unroll
        for (int i = 0; i < 4; ++i) accT[j][i] = (f32x4){0.f, 0.f, 0.f, 0.f};
    {
        bf16x8 ef[4];
#pragma unroll
        for (int i = 0; i < 4; ++i) {
            int er = we + i * 16 + col16;
            ef[i] = *(const bf16x8*)(Ar + er * 32 + (quad ^ (er & 3)) * 8);
        }
#pragma unroll
        for (int j = 0; j < 4; ++j)
#pragma unroll
            for (int i = 0; i < 4; ++i)
                accT[j][i] = __builtin_amdgcn_mfma_f32_16x16x32_bf16(
                    w1f[j], ef[i], accT[j][i], 0, 0, 0);
    }
    // ---- bias+silu -> Hs[edge][hcol], 8B swizzled stores ----
#pragma unroll
    for (int j = 0; j < 4; ++j) {
        int hbase = wh + j * 16 + quad * 4;
        float4 bv = *(const float4*)(b1 + hbase);
#pragma unroll
        for (int i = 0; i < 4; ++i) {
            int edge = we + i * 16 + col16;
            int gph = (hbase >> 3) ^ (edge & 7);
            st4b(Hs + edge * 128 + gph * 8 + (hbase & 7),
                 silu_f(accT[j][i][0] + bv.x), silu_f(accT[j][i][1] + bv.y),
                 silu_f(accT[j][i][2] + bv.z), silu_f(accT[j][i][3] + bv.w));
        }
    }
    __syncthreads();

    // ---- GEMM2 standard orientation; W2 fragment-major from global ----
    const int wm = (wave & 1) * 64;    // edge offset
    const int wn = (wave >> 1) * 64;   // outcol offset
    for (int g = 0; g < 3; ++g) {
        f32x4 acc2[4][4];
#pragma unroll
        for (int i = 0; i < 4; ++i)
#pragma unroll
            for (int j = 0; j < 4; ++j) acc2[i][j] = (f32x4){0.f, 0.f, 0.f, 0.f};
#pragma unroll
        for (int s = 0; s < 4; ++s) {
            bf16x8 a[4], b[4];
#pragma unroll
            for (int i = 0; i < 4; ++i) {
                int er = wm + i * 16 + col16;
                a[i] = *(const bf16x8*)(Hs + er * 128 + ((s * 4 + quad) ^ (er & 7)) * 8);
            }
#pragma unroll
            for (int j = 0; j < 4; ++j) {
                int ob = g * 8 + (wave >> 1) * 4 + j;
                b[j] = *(const bf16x8*)(W2f + (size_t)((ob * 4 + s) * 64 + lane) * 8);
            }
#pragma unroll
            for (int i = 0; i < 4; ++i)
#pragma unroll
                for (int j = 0; j < 4; ++j)
                    acc2[i][j] = __builtin_amdgcn_mfma_f32_16x16x32_bf16(
                        a[i], b[j], acc2[i][j], 0, 0, 0);
        }
        // epilogue: +b2, *cutp -> filc (round-3 column-contiguous pattern)
#pragma unroll
        for (int j = 0; j < 4; ++j) {
            int col = g * 128 + wn + j * 16 + col16;
            float bv = b2[col];
#pragma unroll
            for (int i = 0; i < 4; ++i) {
#pragma unroll
                for (int r = 0; r < 4; ++r) {
                    int row = m0 + wm + i * 16 + quad * 4 + r;
                    float v = (acc2[i][j][r] + bv) * cutp[row];
                    filc[(size_t)row * 384 + col] = __float2bfloat16(v);
                }
            }
        }
    }
}

// Fragment-major weight layouts for fil_fused.
// W1f: [hb 0..7][lane 0..63][e 0..7], hcol = hb*16+(lane&15), k=(lane>>4)*8+e
// W2f: [ob 0..23][s 0..3][lane][e],  outcol = ob*16+(lane&15), k=(s*4+lane>>4)*8+e
__global__ __launch_bounds__(256) void cvt_frag(
    const float* __restrict__ Wf1, const float* __restrict__ Wf2,
    bf16* __restrict__ W1f, bf16* __restrict__ W2f)
{
    int i = blockIdx.x * 256 + threadIdx.x;
    if (i < 4096) {
        int hb = i >> 9, lane = (i >> 3) & 63, e = i & 7;
        int hcol = hb * 16 + (lane & 15);
        int k = (lane >> 4) * 8 + e;
        W1f[i] = __float2bfloat16(k < 20 ? Wf1[k * 128 + hcol] : 0.f);
    } else if (i < 4096 + 49152) {
        int j = i - 4096;
        int ob = j >> 11, s = (j >> 9) & 3, lane = (j >> 3) & 63, e = j & 7;
        int outcol = ob * 16 + (lane & 15);
        int k = (s * 4 + (lane >> 4)) * 8 + e;
        W2f[j] = __float2bfloat16(Wf2[k * 384 + outcol]);
    }
}

// Fused weight transpose+convert for all 7 weights.
struct CvtArgs {
    const float* in[7];
    bf16* out[7];
    int K[7], Nc[7], Kp[7];
    int cum[8];
};
__global__ __launch_bounds__(256) void cvt_all(CvtArgs a)
{
    int i = blockIdx.x * 256 + threadIdx.x;
#pragma unroll
    for (int s = 0; s < 7; ++s) {
        if (i >= a.cum[s] && i < a.cum[s + 1]) {
            int j = i - a.cum[s];
            int n = j / a.Kp[s], k = j - n * a.Kp[s];
            a.out[s][j] = __float2bfloat16(
                k < a.K[s] ? a.in[s][(size_t)k * a.Nc[s] + n] : 0.f);
        }
    }
}

__global__ __launch_bounds__(256) void cvt_bf16(
    const float4* __restrict__ in, bf16* __restrict__ out, size_t n4)
{
    size_t i = (size_t)blockIdx.x * 256 + threadIdx.x;
    if (i >= n4) return;
    float4 v = in[i];
    bf16 t[4] = {__float2bfloat16(v.x), __float2bfloat16(v.y),
                 __float2bfloat16(v.z), __float2bfloat16(v.w)};
    *(bf16x4v*)(out + i * 4) = *(const bf16x4v*)t;
}

__global__ __launch_bounds__(256) void zero_k(float4* __restrict__ p, size_t n4)
{
    size_t i = (size_t)blockIdx.x * 256 + threadIdx.x;
    if (i < n4) p[i] = make_float4(0.f, 0.f, 0.f, 0.f);
}

// ---- counting sort by target ----
__global__ __launch_bounds__(256) void hist_k(
    const int* __restrict__ ei, int* __restrict__ hist, int E)
{
    int e = blockIdx.x * 256 + threadIdx.x;
    if (e < E) atomicAdd(&hist[ei[e]], 1);
}

__global__ __launch_bounds__(256) void scan_k(
    const int* __restrict__ hist, int* __restrict__ off,
    int* __restrict__ cursor, int N, int SLOT1)
{
    __shared__ int ps[257];
    int tid = threadIdx.x;
    int base = tid * 128;
    int s = 0;
    for (int i = 0; i < 128; ++i) s += hist[base + i];
    ps[tid] = s;
    __syncthreads();
    if (tid == 0) {
        int run = 0;
        for (int i = 0; i < 256; ++i) { int t = ps[i]; ps[i] = run; run += t; }
        ps[256] = run;
    }
    __syncthreads();
    int T0 = ps[128];
    int run = ps[tid];
    for (int i = 0; i < 128; ++i) {
        int n = base + i;
        int o = (n < 16384) ? run : SLOT1 + run - T0;
        off[n] = o; cursor[n] = o;
        run += hist[n];
    }
    if (tid == 255) off[N] = SLOT1 + run - T0;
}

__global__ __launch_bounds__(256) void scatter_k(
    const int* __restrict__ ei, const float* __restrict__ uv,
    const float* __restrict__ cut, int* __restrict__ cursor,
    int* __restrict__ perm, int* __restrict__ srcp,
    float* __restrict__ cutp, float* __restrict__ uvp, int E)
{
    int e = blockIdx.x * 256 + threadIdx.x;
    if (e >= E) return;
    int tgt = ei[e];
    int pos = atomicAdd(&cursor[tgt], 1);
    perm[pos] = e;
    srcp[pos] = ei[E + e];
    cutp[pos] = cut[e];
    uvp[pos * 3 + 0] = uv[e * 3 + 0];
    uvp[pos * 3 + 1] = uv[e * 3 + 1];
    uvp[pos * 3 + 2] = uv[e * 3 + 2];
}

// ---- segmented edge reduction: one wave per target, unrolled x2 ----
__global__ __launch_bounds__(256) void edge_seg(
    const bf16* __restrict__ x, const bf16* __restrict__ filt,
    const bf16* __restrict__ mub, const int* __restrict__ srcp,
    const float* __restrict__ uvp, const int* __restrict__ off,
    const int* __restrict__ hist,
    const float* __restrict__ q, const float* __restrict__ mu,
    float* __restrict__ outq, float* __restrict__ outmu,
    int t0, int tcount, int base)
{
    int t = blockIdx.x * 4 + (threadIdx.x >> 6);
    if (t >= tcount) return;
    int n = t0 + t;
    int lane = threadIdx.x & 63;
    int h = lane * 2;
    int p0 = off[n];
    int cnt = hist[n];
    int p1 = p0 + cnt;

    float aq0 = 0.f, aq1 = 0.f;
    float am00 = 0.f, am01 = 0.f, am10 = 0.f, am11 = 0.f, am20 = 0.f, am21 = 0.f;

#define EDGE_LOAD(P, S) \
    const bf16* fp##S = filt + (size_t)((P) - base) * 384; \
    int src##S = srcp[P]; \
    const bf16* xp##S = x + (size_t)src##S * 384; \
    const bf16* mp##S = mub + (size_t)src##S * 384; \
    __hip_bfloat162 fq##S = *(const __hip_bfloat162*)(fp##S + h); \
    __hip_bfloat162 fr##S = *(const __hip_bfloat162*)(fp##S + 128 + h); \
    __hip_bfloat162 fm##S = *(const __hip_bfloat162*)(fp##S + 256 + h); \
    __hip_bfloat162 xq##S = *(const __hip_bfloat162*)(xp##S + h); \
    __hip_bfloat162 xr##S = *(const __hip_bfloat162*)(xp##S + 128 + h); \
    __hip_bfloat162 xm##S = *(const __hip_bfloat162*)(xp##S + 256 + h); \
    __hip_bfloat162 m0##S = *(const __hip_bfloat162*)(mp##S + h); \
    __hip_bfloat162 m1##S = *(const __hip_bfloat162*)(mp##S + 128 + h); \
    __hip_bfloat162 m2##S = *(const __hip_bfloat162*)(mp##S + 256 + h); \
    float u0##S = uvp[(P) * 3 + 0]; \
    float u1##S = uvp[(P) * 3 + 1]; \
    float u2##S = uvp[(P) * 3 + 2];

#define EDGE_ACC(S) { \
    float xq0_ = __bfloat162float(xq##S.x) * __bfloat162float(fq##S.x); \
    float xq1_ = __bfloat162float(xq##S.y) * __bfloat162float(fq##S.y); \
    float xr0_ = __bfloat162float(xr##S.x) * __bfloat162float(fr##S.x); \
    float xr1_ = __bfloat162float(xr##S.y) * __bfloat162float(fr##S.y); \
    float xm0_ = __bfloat162float(xm##S.x) * __bfloat162float(fm##S.x); \
    float xm1_ = __bfloat162float(xm##S.y) * __bfloat162float(fm##S.y); \
    aq0 += xq0_; aq1 += xq1_; \
    am00 += fmaf(u0##S, xr0_, __bfloat162float(m0##S.x) * xm0_); \
    am01 += fmaf(u0##S, xr1_, __bfloat162float(m0##S.y) * xm1_); \
    am10 += fmaf(u1##S, xr0_, __bfloat162float(m1##S.x) * xm0_); \
    am11 += fmaf(u1##S, xr1_, __bfloat162float(m1##S.y) * xm1_); \
    am20 += fmaf(u2##S, xr0_, __bfloat162float(m2##S.x) * xm0_); \
    am21 += fmaf(u2##S, xr1_, __bfloat162float(m2##S.y) * xm1_); }

    int p = p0;
    for (; p + 2 <= p1; p += 2) {
        EDGE_LOAD(p, A)
        EDGE_LOAD(p + 1, B)
        EDGE_ACC(A)
        EDGE_ACC(B)
    }
    if (p < p1) {
        EDGE_LOAD(p, A)
        EDGE_ACC(A)
    }
#undef EDGE_LOAD
#undef EDGE_ACC

    float inv = 1.f / fmaxf((float)cnt, 1.f);
    size_t qb = (size_t)n * 128 + h;
    outq[qb]     = q[qb]     + aq0 * inv;
    outq[qb + 1] = q[qb + 1] + aq1 * inv;
    size_t mb = (size_t)n * 384 + h;
    outmu[mb]       = mu[mb]       + am00 * inv;
    outmu[mb + 1]   = mu[mb + 1]   + am01 * inv;
    outmu[mb + 128] = mu[mb + 128] + am10 * inv;
    outmu[mb + 129] = mu[mb + 129] + am11 * inv;
    outmu[mb + 256] = mu[mb + 256] + am20 * inv;
    outmu[mb + 257] = mu[mb + 257] + am21 * inv;
}

// mcat bf16 [3N][256] -> scin=[q|norm] bf16, inner f32. 2 channels/thread.
__global__ __launch_bounds__(256) void mix_pre(
    const bf16* __restrict__ mcat, const float* __restrict__ outq,
    bf16* __restrict__ scin, float* __restrict__ inner, int N)
{
    int i = blockIdx.x * 256 + threadIdx.x;
    if (i >= N * 64) return;
    int n = i >> 6;
    int h = (i & 63) * 2;
    size_t r = (size_t)n * 768;
    __hip_bfloat162 v0 = *(const __hip_bfloat162*)(mcat + r + h);
    __hip_bfloat162 w0 = *(const __hip_bfloat162*)(mcat + r + 128 + h);
    __hip_bfloat162 v1 = *(const __hip_bfloat162*)(mcat + r + 256 + h);
    __hip_bfloat162 w1 = *(const __hip_bfloat162*)(mcat + r + 384 + h);
    __hip_bfloat162 v2 = *(const __hip_bfloat162*)(mcat + r + 512 + h);
    __hip_bfloat162 w2 = *(const __hip_bfloat162*)(mcat + r + 640 + h);
    float v0x = __bfloat162float(v0.x), v0y = __bfloat162float(v0.y);
    float v1x = __bfloat162float(v1.x), v1y = __bfloat162float(v1.y);
    float v2x = __bfloat162float(v2.x), v2y = __bfloat162float(v2.y);
    float nx = sqrtf(v0x * v0x + v1x * v1x + v2x * v2x + 1e-8f);
    float ny = sqrtf(v0y * v0y + v1y * v1y + v2y * v2y + 1e-8f);
    float ix = v0x * __bfloat162float(w0.x) + v1x * __bfloat162float(w1.x)
             + v2x * __bfloat162float(w2.x);
    float iy = v0y * __bfloat162float(w0.y) + v1y * __bfloat162float(w1.y)
             + v2y * __bfloat162float(w2.y);
    *(float2*)(inner + (size_t)n * 128 + h) = make_float2(ix, iy);
    float2 qv = *(const float2*)(outq + (size_t)n * 128 + h);
    __hip_bfloat162 qb; qb.x = __float2bfloat16(qv.x); qb.y = __float2bfloat16(qv.y);
    __hip_bfloat162 nb; nb.x = __float2bfloat16(nx);  nb.y = __float2bfloat16(ny);
    *(__hip_bfloat162*)(scin + (size_t)n * 256 + h) = qb;
    *(__hip_bfloat162*)(scin + (size_t)n * 256 + 128 + h) = nb;
}

// q += dq + dqmu*inner ; mu += mu_w * dmu_scale. 2 channels/thread.
__global__ __launch_bounds__(256) void mix_post(
    const bf16* __restrict__ delta, const float* __restrict__ inner,
    const bf16* __restrict__ mcat,
    float* __restrict__ outq, float* __restrict__ outmu, int N)
{
    int i = blockIdx.x * 256 + threadIdx.x;
    if (i >= N * 64) return;
    int n = i >> 6;
    int h = (i & 63) * 2;
    size_t dr = (size_t)n * 384;
    __hip_bfloat162 dq2  = *(const __hip_bfloat162*)(delta + dr + h);
    __hip_bfloat162 ds2  = *(const __hip_bfloat162*)(delta + dr + 128 + h);
    __hip_bfloat162 dm2  = *(const __hip_bfloat162*)(delta + dr + 256 + h);
    float2 in2 = *(const float2*)(inner + (size_t)n * 128 + h);
    float2* oq = (float2*)(outq + (size_t)n * 128 + h);
    float2 qv = *oq;
    qv.x += __bfloat162float(dq2.x) + __bfloat162float(dm2.x) * in2.x;
    qv.y += __bfloat162float(dq2.y) + __bfloat162float(dm2.y) * in2.y;
    *oq = qv;
    float dsx = __bfloat162float(ds2.x), dsy = __bfloat162float(ds2.y);
    size_t r = (size_t)n * 768;
    size_t mb = (size_t)n * 384 + h;
    __hip_bfloat162 w0 = *(const __hip_bfloat162*)(mcat + r + 128 + h);
    __hip_bfloat162 w1 = *(const __hip_bfloat162*)(mcat + r + 384 + h);
    __hip_bfloat162 w2 = *(const __hip_bfloat162*)(mcat + r + 640 + h);
    float2* om0 = (float2*)(outmu + mb);
    float2* om1 = (float2*)(outmu + mb + 128);
    float2* om2 = (float2*)(outmu + mb + 256);
    float2 a0 = *om0, a1 = *om1, a2 = *om2;
    a0.x += __bfloat162float(w0.x) * dsx; a0.y += __bfloat162float(w0.y) * dsy;
    a1.x += __bfloat162float(w1.x) * dsx; a1.y += __bfloat162float(w1.y) * dsy;
    a2.x += __bfloat162float(w2.x) * dsx; a2.y += __bfloat162float(w2.y) * dsy;
    *om0 = a0; *om1 = a1; *om2 = a2;
}

extern "C" void kernel_launch(void* const* d_in, const int* in_sizes, int n_in,
                              void* d_out, int out_size, void* d_ws, size_t ws_size,
                              hipStream_t stream)
{
    const float* q   = (const float*)d_in[0];
    const float* mu  = (const float*)d_in[1];
    const int*   ei  = (const int*)d_in[2];
    const float* rbf = (const float*)d_in[3];
    const float* uv  = (const float*)d_in[4];
    const float* cut = (const float*)d_in[5];
    const float* Wi1 = (const float*)d_in[6];
    const float* bi1 = (const float*)d_in[7];
    const float* Wi2 = (const float*)d_in[8];
    const float* bi2 = (const float*)d_in[9];
    const float* Wf1 = (const float*)d_in[10];
    const float* bf1 = (const float*)d_in[11];
    const float* Wf2 = (const float*)d_in[12];
    const float* bf2 = (const float*)d_in[13];
    const float* Wv  = (const float*)d_in[14];
    const float* Ws1 = (const float*)d_in[15];
    const float* bs1 = (const float*)d_in[16];
    const float* Ws2 = (const float*)d_in[17];
    const float* bs2 = (const float*)d_in[18];

    const int H = 128;
    const int N = in_sizes[0] / H;   // 32768
    const int E = in_sizes[5];       // 262144
    const int SLOT1 = E / 2 + 4096;  // 135168, %128==0
    (void)n_in; (void)out_size;

    // ---- workspace layout ----
    char* ws = (char*)d_ws;
    size_t o = 0;
    auto take = [&](size_t b) { char* p = ws + o; o += (b + 255) & ~(size_t)255; return p; };
    bf16*  xb     = (bf16*)take((size_t)N * 384 * 2);        // 25.2 MB [P1..P3]
    bf16*  mub    = (bf16*)take((size_t)N * 384 * 2);        // 25.2 MB [P3]
    bf16*  filc   = (bf16*)take((size_t)SLOT1 * 384 * 2);    // 103.8 MB [P3]
    bf16*  hf     = (bf16*)take((size_t)SLOT1 * 128 * 2);    // 34.6 MB (unused)
    int*   perm   = (int*)take((size_t)2 * SLOT1 * 4);
    int*   srcp   = (int*)take((size_t)2 * SLOT1 * 4);
    float* cutp   = (float*)take((size_t)2 * SLOT1 * 4);
    float* uvp    = (float*)take((size_t)2 * SLOT1 * 12);
    int*   hist   = (int*)take((size_t)N * 4);
    int*   off    = (int*)take((size_t)(N + 64) * 4);
    int*   cursor = (int*)take((size_t)N * 4);
    bf16*  wts    = (bf16*)take(1300000);
    if (o > ws_size) return;
    (void)hf;
    // P5 aliases (xb/mub/filc dead): 134.3 MB < 188.8 MB transient region
    bf16*  mcat  = (bf16*)ws;
    bf16*  scin  = mcat + (size_t)N * 768;
    float* inner = (float*)(scin + (size_t)N * 256);
    bf16*  s1    = (bf16*)(inner + (size_t)N * 128);
    bf16*  delta = s1 + (size_t)N * 384;

    bf16* Wi1t = wts;             // [384][128]
    bf16* Wi2t = Wi1t + 49152;    // [384][384]
    bf16* Wf1t = Wi2t + 147456;   // [128][32]   (legacy, unused)
    bf16* Wf2t = Wf1t + 4096;     // [384][128]  (legacy, unused)
    bf16* Wvt  = Wf2t + 49152;    // [256][128]
    bf16* Ws1t = Wvt  + 32768;    // [384][256]
    bf16* Ws2t = Ws1t + 98304;    // [384][384]
    bf16* W1f  = Ws2t + 147456;   // fragment-major, 4096
    bf16* W2f  = W1f  + 4096;     // fragment-major, 49152

    float* outq  = (float*)d_out;
    float* outmu = outq + (size_t)N * 128;

    dim3 blk(256);

    // ---- P0: weights -> bf16 transposed + fragment-major; mu -> bf16 ----
    {
        CvtArgs a;
        const float* wi[7] = {Wi1, Wi2, Wf1, Wf2, Wv, Ws1, Ws2};
        bf16* wo[7] = {Wi1t, Wi2t, Wf1t, Wf2t, Wvt, Ws1t, Ws2t};
        int K[7]  = {128, 384, 20, 128, 128, 256, 384};
        int Nc[7] = {384, 384, 128, 384, 256, 384, 384};
        int Kp[7] = {128, 384, 32, 128, 128, 256, 384};
        int c = 0;
        for (int s = 0; s < 7; ++s) {
            a.in[s] = wi[s]; a.out[s] = wo[s];
            a.K[s] = K[s]; a.Nc[s] = Nc[s]; a.Kp[s] = Kp[s];
            a.cum[s] = c; c += Nc[s] * Kp[s];
        }
        a.cum[7] = c;
        cvt_all<<<dim3((c + 255) / 256), blk, 0, stream>>>(a);
        cvt_frag<<<dim3((4096 + 49152 + 255) / 256), blk, 0, stream>>>(
            Wf1, Wf2, W1f, W2f);
        cvt_bf16<<<dim3((unsigned)((size_t)N * 384 / 4 / 256)), blk, 0, stream>>>(
            (const float4*)mu, mub, (size_t)N * 384 / 4);
    }

    // ---- P1: interaction MLP (full) ----
    {
        bf16* x1 = filc;   // scratch
        mgemm<float, bf16, 1><<<dim3(N / 128, 3), blk, 0, stream>>>(
            q, Wi1t, bi1, nullptr, x1, N, 128, 384, 128);
        mgemm<bf16, bf16, 0><<<dim3(N / 128, 3), blk, 0, stream>>>(
            x1, Wi2t, bi2, nullptr, xb, N, 384, 384, 0);
    }

    // ---- PS: counting sort by target ----
    zero_k<<<dim3((N / 4 + 255) / 256), blk, 0, stream>>>((float4*)hist, N / 4);
    hist_k<<<dim3(E / 256), blk, 0, stream>>>(ei, hist, E);
    scan_k<<<dim3(1), blk, 0, stream>>>(hist, off, cursor, N, SLOT1);
    scatter_k<<<dim3(E / 256), blk, 0, stream>>>(ei, uv, cut, cursor,
                                                 perm, srcp, cutp, uvp, E);

    // ---- P3: fused filter pipeline + segmented edge reduce, 2 chunks ----
    for (int c = 0; c < 2; ++c) {
        int base = c * SLOT1;
        fil_fused<<<dim3(SLOT1 / 128), blk, 0, stream>>>(
            rbf, W1f, bf1, W2f, bf2, cutp + base, perm + base, filc,
            (unsigned)(E - 1));
        edge_seg<<<dim3(16384 / 4), blk, 0, stream>>>(
            xb, filc, mub, srcp, uvp, off, hist, q, mu, outq, outmu,
            c * 16384, 16384, base);
    }

    // ---- P5: mixing (full) ----
    mgemm<float, bf16, 0><<<dim3(3 * N / 128, 2), blk, 0, stream>>>(
        outmu, Wvt, nullptr, nullptr, mcat, 3 * N, 128, 256, 128);
    mix_pre<<<dim3(N * 64 / 256), blk, 0, stream>>>(mcat, outq, scin, inner, N);
    mgemm<bf16, bf16, 1><<<dim3(N / 128, 3), blk, 0, stream>>>(
        scin, Ws1t, bs1, nullptr, s1, N, 256, 384, 0);
    mgemm<bf16, bf16, 0><<<dim3(N / 128, 3), blk, 0, stream>>>(
        s1, Ws2t, bs2, nullptr, delta, N, 384, 384, 0);
    mix_post<<<dim3(N * 64 / 256), blk, 0, stream>>>(delta, inner, mcat,
                                                     outq, outmu, N);
}

// Round 6
// 598.859 us; speedup vs baseline: 1.2980x; 1.2980x over previous
//
#include <hip/hip_runtime.h>
#include <hip/hip_bf16.h>

typedef __hip_bfloat16 bf16;
typedef __attribute__((ext_vector_type(8))) short bf16x8;
typedef __attribute__((ext_vector_type(4))) short bf16x4v;
typedef __attribute__((ext_vector_type(4))) float f32x4;

__device__ __forceinline__ void gload_lds16(const void* g, void* l)
{
    __builtin_amdgcn_global_load_lds(
        (const __attribute__((address_space(1))) void*)g,
        (__attribute__((address_space(3))) void*)l, 16, 0, 0);
}

__device__ __forceinline__ float silu_f(float v) { return v / (1.f + expf(-v)); }

__device__ __forceinline__ void st4b(bf16* p, float a, float b, float c, float d)
{
    bf16 t[4] = {__float2bfloat16(a), __float2bfloat16(b),
                 __float2bfloat16(c), __float2bfloat16(d)};
    *(bf16x4v*)p = *(const bf16x4v*)t;
}

// ---------------------------------------------------------------------------
// MFMA bf16 GEMM: C = epi(A @ Bt^T + bias), K % 64 == 0.
// BK=64 single-buffered, XOR-swizzled LDS (conflict-free, round-3 proven).
// ---------------------------------------------------------------------------
template<typename TA, typename TC, int EPI>
__global__ __launch_bounds__(256) void mgemm(
    const TA* __restrict__ A, const bf16* __restrict__ Bt,
    const float* __restrict__ bias, const float* __restrict__ rowscale,
    TC* __restrict__ C, int M, int K, int N, int ka)
{
    __shared__ __align__(16) bf16 As[128 * 64];
    __shared__ __align__(16) bf16 Bs[128 * 64];
    const int tid = threadIdx.x;
    const int lane = tid & 63;
    const int wave = tid >> 6;
    const int col16 = lane & 15;
    const int quad = lane >> 4;
    const int wm = (wave & 1) * 64;
    const int wn = (wave >> 1) * 64;
    const size_t m0 = (size_t)blockIdx.x * 128;
    const int n0 = blockIdx.y * 128;

    f32x4 acc[4][4];
#pragma unroll
    for (int i = 0; i < 4; ++i)
#pragma unroll
        for (int j = 0; j < 4; ++j) acc[i][j] = (f32x4){0.f, 0.f, 0.f, 0.f};

    const int rloc = lane >> 3;      // row within 8-row gload group
    const int gpos = lane & 7;       // granule position within row

    for (int kc = 0; kc < K; kc += 64) {
        // ---- stage A ----
        if constexpr (sizeof(TA) == 2) {
#pragma unroll
            for (int i = 0; i < 4; ++i) {
                int row = wave * 32 + i * 8 + rloc;
                int gs = gpos ^ (row & 7);
                gload_lds16((const bf16*)A + (m0 + row) * (size_t)K + kc + gs * 8,
                            As + (wave * 32 + i * 8) * 64);
            }
        } else {
#pragma unroll
            for (int r = 0; r < 4; ++r) {
                int slot = tid + 256 * r;         // 0..1023
                int row = slot >> 3;              // 0..127
                int gl = slot & 7;                // logical granule
                int gp = gl ^ (row & 7);          // phys granule
                int kg = kc + gl * 8;
                const float* ap = (const float*)A + (m0 + row) * (size_t)ka + kg;
                float4 v0 = make_float4(0.f, 0.f, 0.f, 0.f), v1 = v0;
                if (kg < ka) v0 = *(const float4*)ap;
                if (kg + 4 < ka) v1 = *(const float4*)(ap + 4);
                bf16 t[8] = {__float2bfloat16(v0.x), __float2bfloat16(v0.y),
                             __float2bfloat16(v0.z), __float2bfloat16(v0.w),
                             __float2bfloat16(v1.x), __float2bfloat16(v1.y),
                             __float2bfloat16(v1.z), __float2bfloat16(v1.w)};
                *(bf16x8*)(As + row * 64 + gp * 8) = *(const bf16x8*)t;
            }
        }
        // ---- stage B ----
#pragma unroll
        for (int i = 0; i < 4; ++i) {
            int row = wave * 32 + i * 8 + rloc;
            int gs = gpos ^ (row & 7);
            gload_lds16(Bt + (size_t)(n0 + row) * K + kc + gs * 8,
                        Bs + (wave * 32 + i * 8) * 64);
        }
        __syncthreads();

#pragma unroll
        for (int s = 0; s < 2; ++s) {
            bf16x8 a[4], b[4];
#pragma unroll
            for (int i = 0; i < 4; ++i) {
                int row = wm + i * 16 + col16;
                a[i] = *(const bf16x8*)(As + row * 64 + ((s * 4 + quad) ^ (row & 7)) * 8);
            }
#pragma unroll
            for (int j = 0; j < 4; ++j) {
                int row = wn + j * 16 + col16;
                b[j] = *(const bf16x8*)(Bs + row * 64 + ((s * 4 + quad) ^ (row & 7)) * 8);
            }
#pragma unroll
            for (int i = 0; i < 4; ++i)
#pragma unroll
                for (int j = 0; j < 4; ++j)
                    acc[i][j] = __builtin_amdgcn_mfma_f32_16x16x32_bf16(a[i], b[j], acc[i][j], 0, 0, 0);
        }
        __syncthreads();
    }

#pragma unroll
    for (int j = 0; j < 4; ++j) {
        int col = n0 + wn + j * 16 + col16;
        float bv = bias ? bias[col] : 0.f;
#pragma unroll
        for (int i = 0; i < 4; ++i) {
#pragma unroll
            for (int r = 0; r < 4; ++r) {
                size_t row = m0 + wm + i * 16 + quad * 4 + r;
                float v = acc[i][j][r] + bv;
                if (EPI == 1) v = silu_f(v);
                if (EPI == 2) v *= rowscale[row];
                if constexpr (sizeof(TC) == 2)
                    ((bf16*)C)[row * (size_t)N + col] = __float2bfloat16(v);
                else
                    ((float*)C)[row * (size_t)N + col] = v;
            }
        }
    }
}

// ---------------------------------------------------------------------------
// Fused filter pipeline (round-3 structure; GEMM1 swapped for 8B Hs stores):
//   h = silu(rbf[perm] @ W1t + b1)   (K=20 pad 32, LDS only)
//   filc = (h @ W2t + b2) * cutp     (3 col-groups, W2 LDS-staged, barriers
//                                     between groups keep filc line writes
//                                     temporally dense -> no L2 RMW)
// GEMM1 operand-swapped: accT[hcol][edge] -> each thread's 4 acc values are
// contiguous along hcol -> 16x 8B swizzled ds_write (was 64x 2B scalars,
// 1.76M bank conflicts in round 3).
// ---------------------------------------------------------------------------
__global__ __launch_bounds__(256) void fil_fused(
    const float* __restrict__ rbf, const bf16* __restrict__ W1t,
    const float* __restrict__ b1, const bf16* __restrict__ W2t,
    const float* __restrict__ b2, const float* __restrict__ cutp,
    const int* __restrict__ perm, bf16* __restrict__ filc, unsigned apmask)
{
    __shared__ __align__(16) bf16 Ar[128 * 32];   // 8 KB
    __shared__ __align__(16) bf16 W1[128 * 32];   // 8 KB
    __shared__ __align__(16) bf16 Hs[128 * 128];  // 32 KB
    __shared__ __align__(16) bf16 W2[128 * 128];  // 32 KB
    const int tid = threadIdx.x;
    const int lane = tid & 63;
    const int wave = tid >> 6;
    const int col16 = lane & 15;
    const int quad = lane >> 4;
    const int wm = (wave & 1) * 64;   // edge offset
    const int wn = (wave >> 1) * 64;  // hcol/outcol offset
    const int m0 = blockIdx.x * 128;

    // ---- stage Ar: rbf gather f32->bf16, 4 granules/row, swz (row&3) ----
#pragma unroll
    for (int r = 0; r < 2; ++r) {
        int slot = tid + 256 * r;       // 0..511
        int row = slot >> 2;
        int gl = slot & 3;
        int gp = gl ^ (row & 3);
        size_t arow = (size_t)(unsigned)(perm[m0 + row] & (int)apmask);
        int kg = gl * 8;
        const float* ap = rbf + arow * 20 + kg;
        float4 v0 = make_float4(0.f, 0.f, 0.f, 0.f), v1 = v0;
        if (kg < 20) v0 = *(const float4*)ap;
        if (kg + 4 < 20) v1 = *(const float4*)(ap + 4);
        bf16 t[8] = {__float2bfloat16(v0.x), __float2bfloat16(v0.y),
                     __float2bfloat16(v0.z), __float2bfloat16(v0.w),
                     __float2bfloat16(v1.x), __float2bfloat16(v1.y),
                     __float2bfloat16(v1.z), __float2bfloat16(v1.w)};
        *(bf16x8*)(Ar + row * 32 + gp * 8) = *(const bf16x8*)t;
    }
    // ---- stage W1 [128][32] via gload, pre-swizzled source ----
#pragma unroll
    for (int i = 0; i < 2; ++i) {
        int row = wave * 32 + i * 16 + (lane >> 2);
        int gs = (lane & 3) ^ (row & 3);
        gload_lds16(W1t + row * 32 + gs * 8, W1 + (wave * 32 + i * 16) * 32);
    }
    __syncthreads();

    // ---- GEMM1 swapped: accT[j][i] = h^T tile [hcol][edge] ----
    f32x4 accT[4][4];
#pragma unroll
    for (int j = 0; j < 4; ++j)
#pragma unroll
        for (int i = 0; i < 4; ++i) accT[j][i] = (f32x4){0.f, 0.f, 0.f, 0.f};
    {
        bf16x8 a[4], b[4];
#pragma unroll
        for (int i = 0; i < 4; ++i) {
            int row = wm + i * 16 + col16;
            a[i] = *(const bf16x8*)(Ar + row * 32 + (quad ^ (row & 3)) * 8);
        }
#pragma unroll
        for (int j = 0; j < 4; ++j) {
            int row = wn + j * 16 + col16;
            b[j] = *(const bf16x8*)(W1 + row * 32 + (quad ^ (row & 3)) * 8);
        }
#pragma unroll
        for (int j = 0; j < 4; ++j)
#pragma unroll
            for (int i = 0; i < 4; ++i)
                accT[j][i] = __builtin_amdgcn_mfma_f32_16x16x32_bf16(
                    b[j], a[i], accT[j][i], 0, 0, 0);
    }
    // ---- bias+silu -> Hs[edge][hcol], 16x 8B swizzled stores ----
#pragma unroll
    for (int j = 0; j < 4; ++j) {
        int hbase = wn + j * 16 + quad * 4;
        float4 bv = *(const float4*)(b1 + hbase);
#pragma unroll
        for (int i = 0; i < 4; ++i) {
            int edge = wm + i * 16 + col16;
            int gph = (hbase >> 3) ^ (edge & 7);
            st4b(Hs + edge * 128 + gph * 8 + (hbase & 7),
                 silu_f(accT[j][i][0] + bv.x), silu_f(accT[j][i][1] + bv.y),
                 silu_f(accT[j][i][2] + bv.z), silu_f(accT[j][i][3] + bv.w));
        }
    }
    // ---- stage W2 group 0 ----
#pragma unroll
    for (int i = 0; i < 8; ++i) {
        int row = wave * 32 + i * 4 + (lane >> 4);
        int gs = (lane & 15) ^ (row & 7);
        gload_lds16(W2t + (size_t)row * 128 + gs * 8, W2 + (wave * 32 + i * 4) * 128);
    }
    __syncthreads();

    for (int g = 0; g < 3; ++g) {
        f32x4 acc[4][4];
#pragma unroll
        for (int i = 0; i < 4; ++i)
#pragma unroll
            for (int j = 0; j < 4; ++j) acc[i][j] = (f32x4){0.f, 0.f, 0.f, 0.f};
#pragma unroll
        for (int s = 0; s < 4; ++s) {
            bf16x8 a[4], b[4];
#pragma unroll
            for (int i = 0; i < 4; ++i) {
                int row = wm + i * 16 + col16;
                a[i] = *(const bf16x8*)(Hs + row * 128 + ((s * 4 + quad) ^ (row & 7)) * 8);
            }
#pragma unroll
            for (int j = 0; j < 4; ++j) {
                int row = wn + j * 16 + col16;
                b[j] = *(const bf16x8*)(W2 + row * 128 + ((s * 4 + quad) ^ (row & 7)) * 8);
            }
#pragma unroll
            for (int i = 0; i < 4; ++i)
#pragma unroll
                for (int j = 0; j < 4; ++j)
                    acc[i][j] = __builtin_amdgcn_mfma_f32_16x16x32_bf16(
                        a[i], b[j], acc[i][j], 0, 0, 0);
        }
        __syncthreads();   // W2/Hs reads done
        if (g < 2) {
#pragma unroll
            for (int i = 0; i < 8; ++i) {
                int row = wave * 32 + i * 4 + (lane >> 4);
                int gs = (lane & 15) ^ (row & 7);
                gload_lds16(W2t + (size_t)((g + 1) * 128 + row) * 128 + gs * 8,
                            W2 + (wave * 32 + i * 4) * 128);
            }
        }
        // ---- epilogue: +b2, *cutp -> filc ----
#pragma unroll
        for (int j = 0; j < 4; ++j) {
            int col = g * 128 + wn + j * 16 + col16;
            float bv = b2[col];
#pragma unroll
            for (int i = 0; i < 4; ++i) {
#pragma unroll
                for (int r = 0; r < 4; ++r) {
                    int row = m0 + wm + i * 16 + quad * 4 + r;
                    float v = (acc[i][j][r] + bv) * cutp[row];
                    filc[(size_t)row * 384 + col] = __float2bfloat16(v);
                }
            }
        }
        if (g < 2) __syncthreads();   // W2(g+1) staged
    }
}

// Fused weight transpose+convert for all 7 weights.
struct CvtArgs {
    const float* in[7];
    bf16* out[7];
    int K[7], Nc[7], Kp[7];
    int cum[8];
};
__global__ __launch_bounds__(256) void cvt_all(CvtArgs a)
{
    int i = blockIdx.x * 256 + threadIdx.x;
#pragma unroll
    for (int s = 0; s < 7; ++s) {
        if (i >= a.cum[s] && i < a.cum[s + 1]) {
            int j = i - a.cum[s];
            int n = j / a.Kp[s], k = j - n * a.Kp[s];
            a.out[s][j] = __float2bfloat16(
                k < a.K[s] ? a.in[s][(size_t)k * a.Nc[s] + n] : 0.f);
        }
    }
}

__global__ __launch_bounds__(256) void cvt_bf16(
    const float4* __restrict__ in, bf16* __restrict__ out, size_t n4)
{
    size_t i = (size_t)blockIdx.x * 256 + threadIdx.x;
    if (i >= n4) return;
    float4 v = in[i];
    bf16 t[4] = {__float2bfloat16(v.x), __float2bfloat16(v.y),
                 __float2bfloat16(v.z), __float2bfloat16(v.w)};
    *(bf16x4v*)(out + i * 4) = *(const bf16x4v*)t;
}

__global__ __launch_bounds__(256) void zero_k(float4* __restrict__ p, size_t n4)
{
    size_t i = (size_t)blockIdx.x * 256 + threadIdx.x;
    if (i < n4) p[i] = make_float4(0.f, 0.f, 0.f, 0.f);
}

// ---- counting sort by target ----
__global__ __launch_bounds__(256) void hist_k(
    const int* __restrict__ ei, int* __restrict__ hist, int E)
{
    int e = blockIdx.x * 256 + threadIdx.x;
    if (e < E) atomicAdd(&hist[ei[e]], 1);
}

__global__ __launch_bounds__(256) void scan_k(
    const int* __restrict__ hist, int* __restrict__ off,
    int* __restrict__ cursor, int N, int SLOT1)
{
    __shared__ int ps[257];
    int tid = threadIdx.x;
    int base = tid * 128;
    int s = 0;
    for (int i = 0; i < 128; ++i) s += hist[base + i];
    ps[tid] = s;
    __syncthreads();
    if (tid == 0) {
        int run = 0;
        for (int i = 0; i < 256; ++i) { int t = ps[i]; ps[i] = run; run += t; }
        ps[256] = run;
    }
    __syncthreads();
    int T0 = ps[128];
    int run = ps[tid];
    for (int i = 0; i < 128; ++i) {
        int n = base + i;
        int o = (n < 16384) ? run : SLOT1 + run - T0;
        off[n] = o; cursor[n] = o;
        run += hist[n];
    }
    if (tid == 255) off[N] = SLOT1 + run - T0;
}

__global__ __launch_bounds__(256) void scatter_k(
    const int* __restrict__ ei, const float* __restrict__ uv,
    const float* __restrict__ cut, int* __restrict__ cursor,
    int* __restrict__ perm, int* __restrict__ srcp,
    float* __restrict__ cutp, float* __restrict__ uvp, int E)
{
    int e = blockIdx.x * 256 + threadIdx.x;
    if (e >= E) return;
    int tgt = ei[e];
    int pos = atomicAdd(&cursor[tgt], 1);
    perm[pos] = e;
    srcp[pos] = ei[E + e];
    cutp[pos] = cut[e];
    uvp[pos * 3 + 0] = uv[e * 3 + 0];
    uvp[pos * 3 + 1] = uv[e * 3 + 1];
    uvp[pos * 3 + 2] = uv[e * 3 + 2];
}

// ---- segmented edge reduction: one wave per target, unrolled x2 ----
__global__ __launch_bounds__(256) void edge_seg(
    const bf16* __restrict__ x, const bf16* __restrict__ filt,
    const bf16* __restrict__ mub, const int* __restrict__ srcp,
    const float* __restrict__ uvp, const int* __restrict__ off,
    const int* __restrict__ hist,
    const float* __restrict__ q, const float* __restrict__ mu,
    float* __restrict__ outq, float* __restrict__ outmu,
    int t0, int tcount, int base)
{
    int t = blockIdx.x * 4 + (threadIdx.x >> 6);
    if (t >= tcount) return;
    int n = t0 + t;
    int lane = threadIdx.x & 63;
    int h = lane * 2;
    int p0 = off[n];
    int cnt = hist[n];
    int p1 = p0 + cnt;

    float aq0 = 0.f, aq1 = 0.f;
    float am00 = 0.f, am01 = 0.f, am10 = 0.f, am11 = 0.f, am20 = 0.f, am21 = 0.f;

#define EDGE_LOAD(P, S) \
    const bf16* fp##S = filt + (size_t)((P) - base) * 384; \
    int src##S = srcp[P]; \
    const bf16* xp##S = x + (size_t)src##S * 384; \
    const bf16* mp##S = mub + (size_t)src##S * 384; \
    __hip_bfloat162 fq##S = *(const __hip_bfloat162*)(fp##S + h); \
    __hip_bfloat162 fr##S = *(const __hip_bfloat162*)(fp##S + 128 + h); \
    __hip_bfloat162 fm##S = *(const __hip_bfloat162*)(fp##S + 256 + h); \
    __hip_bfloat162 xq##S = *(const __hip_bfloat162*)(xp##S + h); \
    __hip_bfloat162 xr##S = *(const __hip_bfloat162*)(xp##S + 128 + h); \
    __hip_bfloat162 xm##S = *(const __hip_bfloat162*)(xp##S + 256 + h); \
    __hip_bfloat162 m0##S = *(const __hip_bfloat162*)(mp##S + h); \
    __hip_bfloat162 m1##S = *(const __hip_bfloat162*)(mp##S + 128 + h); \
    __hip_bfloat162 m2##S = *(const __hip_bfloat162*)(mp##S + 256 + h); \
    float u0##S = uvp[(P) * 3 + 0]; \
    float u1##S = uvp[(P) * 3 + 1]; \
    float u2##S = uvp[(P) * 3 + 2];

#define EDGE_ACC(S) { \
    float xq0_ = __bfloat162float(xq##S.x) * __bfloat162float(fq##S.x); \
    float xq1_ = __bfloat162float(xq##S.y) * __bfloat162float(fq##S.y); \
    float xr0_ = __bfloat162float(xr##S.x) * __bfloat162float(fr##S.x); \
    float xr1_ = __bfloat162float(xr##S.y) * __bfloat162float(fr##S.y); \
    float xm0_ = __bfloat162float(xm##S.x) * __bfloat162float(fm##S.x); \
    float xm1_ = __bfloat162float(xm##S.y) * __bfloat162float(fm##S.y); \
    aq0 += xq0_; aq1 += xq1_; \
    am00 += fmaf(u0##S, xr0_, __bfloat162float(m0##S.x) * xm0_); \
    am01 += fmaf(u0##S, xr1_, __bfloat162float(m0##S.y) * xm1_); \
    am10 += fmaf(u1##S, xr0_, __bfloat162float(m1##S.x) * xm0_); \
    am11 += fmaf(u1##S, xr1_, __bfloat162float(m1##S.y) * xm1_); \
    am20 += fmaf(u2##S, xr0_, __bfloat162float(m2##S.x) * xm0_); \
    am21 += fmaf(u2##S, xr1_, __bfloat162float(m2##S.y) * xm1_); }

    int p = p0;
    for (; p + 2 <= p1; p += 2) {
        EDGE_LOAD(p, A)
        EDGE_LOAD(p + 1, B)
        EDGE_ACC(A)
        EDGE_ACC(B)
    }
    if (p < p1) {
        EDGE_LOAD(p, A)
        EDGE_ACC(A)
    }
#undef EDGE_LOAD
#undef EDGE_ACC

    float inv = 1.f / fmaxf((float)cnt, 1.f);
    size_t qb = (size_t)n * 128 + h;
    outq[qb]     = q[qb]     + aq0 * inv;
    outq[qb + 1] = q[qb + 1] + aq1 * inv;
    size_t mb = (size_t)n * 384 + h;
    outmu[mb]       = mu[mb]       + am00 * inv;
    outmu[mb + 1]   = mu[mb + 1]   + am01 * inv;
    outmu[mb + 128] = mu[mb + 128] + am10 * inv;
    outmu[mb + 129] = mu[mb + 129] + am11 * inv;
    outmu[mb + 256] = mu[mb + 256] + am20 * inv;
    outmu[mb + 257] = mu[mb + 257] + am21 * inv;
}

// mcat bf16 [3N][256] -> scin=[q|norm] bf16, inner f32. 2 channels/thread.
__global__ __launch_bounds__(256) void mix_pre(
    const bf16* __restrict__ mcat, const float* __restrict__ outq,
    bf16* __restrict__ scin, float* __restrict__ inner, int N)
{
    int i = blockIdx.x * 256 + threadIdx.x;
    if (i >= N * 64) return;
    int n = i >> 6;
    int h = (i & 63) * 2;
    size_t r = (size_t)n * 768;
    __hip_bfloat162 v0 = *(const __hip_bfloat162*)(mcat + r + h);
    __hip_bfloat162 w0 = *(const __hip_bfloat162*)(mcat + r + 128 + h);
    __hip_bfloat162 v1 = *(const __hip_bfloat162*)(mcat + r + 256 + h);
    __hip_bfloat162 w1 = *(const __hip_bfloat162*)(mcat + r + 384 + h);
    __hip_bfloat162 v2 = *(const __hip_bfloat162*)(mcat + r + 512 + h);
    __hip_bfloat162 w2 = *(const __hip_bfloat162*)(mcat + r + 640 + h);
    float v0x = __bfloat162float(v0.x), v0y = __bfloat162float(v0.y);
    float v1x = __bfloat162float(v1.x), v1y = __bfloat162float(v1.y);
    float v2x = __bfloat162float(v2.x), v2y = __bfloat162float(v2.y);
    float nx = sqrtf(v0x * v0x + v1x * v1x + v2x * v2x + 1e-8f);
    float ny = sqrtf(v0y * v0y + v1y * v1y + v2y * v2y + 1e-8f);
    float ix = v0x * __bfloat162float(w0.x) + v1x * __bfloat162float(w1.x)
             + v2x * __bfloat162float(w2.x);
    float iy = v0y * __bfloat162float(w0.y) + v1y * __bfloat162float(w1.y)
             + v2y * __bfloat162float(w2.y);
    *(float2*)(inner + (size_t)n * 128 + h) = make_float2(ix, iy);
    float2 qv = *(const float2*)(outq + (size_t)n * 128 + h);
    __hip_bfloat162 qb; qb.x = __float2bfloat16(qv.x); qb.y = __float2bfloat16(qv.y);
    __hip_bfloat162 nb; nb.x = __float2bfloat16(nx);  nb.y = __float2bfloat16(ny);
    *(__hip_bfloat162*)(scin + (size_t)n * 256 + h) = qb;
    *(__hip_bfloat162*)(scin + (size_t)n * 256 + 128 + h) = nb;
}

// q += dq + dqmu*inner ; mu += mu_w * dmu_scale. 2 channels/thread.
__global__ __launch_bounds__(256) void mix_post(
    const bf16* __restrict__ delta, const float* __restrict__ inner,
    const bf16* __restrict__ mcat,
    float* __restrict__ outq, float* __restrict__ outmu, int N)
{
    int i = blockIdx.x * 256 + threadIdx.x;
    if (i >= N * 64) return;
    int n = i >> 6;
    int h = (i & 63) * 2;
    size_t dr = (size_t)n * 384;
    __hip_bfloat162 dq2  = *(const __hip_bfloat162*)(delta + dr + h);
    __hip_bfloat162 ds2  = *(const __hip_bfloat162*)(delta + dr + 128 + h);
    __hip_bfloat162 dm2  = *(const __hip_bfloat162*)(delta + dr + 256 + h);
    float2 in2 = *(const float2*)(inner + (size_t)n * 128 + h);
    float2* oq = (float2*)(outq + (size_t)n * 128 + h);
    float2 qv = *oq;
    qv.x += __bfloat162float(dq2.x) + __bfloat162float(dm2.x) * in2.x;
    qv.y += __bfloat162float(dq2.y) + __bfloat162float(dm2.y) * in2.y;
    *oq = qv;
    float dsx = __bfloat162float(ds2.x), dsy = __bfloat162float(ds2.y);
    size_t r = (size_t)n * 768;
    size_t mb = (size_t)n * 384 + h;
    __hip_bfloat162 w0 = *(const __hip_bfloat162*)(mcat + r + 128 + h);
    __hip_bfloat162 w1 = *(const __hip_bfloat162*)(mcat + r + 384 + h);
    __hip_bfloat162 w2 = *(const __hip_bfloat162*)(mcat + r + 640 + h);
    float2* om0 = (float2*)(outmu + mb);
    float2* om1 = (float2*)(outmu + mb + 128);
    float2* om2 = (float2*)(outmu + mb + 256);
    float2 a0 = *om0, a1 = *om1, a2 = *om2;
    a0.x += __bfloat162float(w0.x) * dsx; a0.y += __bfloat162float(w0.y) * dsy;
    a1.x += __bfloat162float(w1.x) * dsx; a1.y += __bfloat162float(w1.y) * dsy;
    a2.x += __bfloat162float(w2.x) * dsx; a2.y += __bfloat162float(w2.y) * dsy;
    *om0 = a0; *om1 = a1; *om2 = a2;
}

extern "C" void kernel_launch(void* const* d_in, const int* in_sizes, int n_in,
                              void* d_out, int out_size, void* d_ws, size_t ws_size,
                              hipStream_t stream)
{
    const float* q   = (const float*)d_in[0];
    const float* mu  = (const float*)d_in[1];
    const int*   ei  = (const int*)d_in[2];
    const float* rbf = (const float*)d_in[3];
    const float* uv  = (const float*)d_in[4];
    const float* cut = (const float*)d_in[5];
    const float* Wi1 = (const float*)d_in[6];
    const float* bi1 = (const float*)d_in[7];
    const float* Wi2 = (const float*)d_in[8];
    const float* bi2 = (const float*)d_in[9];
    const float* Wf1 = (const float*)d_in[10];
    const float* bf1 = (const float*)d_in[11];
    const float* Wf2 = (const float*)d_in[12];
    const float* bf2 = (const float*)d_in[13];
    const float* Wv  = (const float*)d_in[14];
    const float* Ws1 = (const float*)d_in[15];
    const float* bs1 = (const float*)d_in[16];
    const float* Ws2 = (const float*)d_in[17];
    const float* bs2 = (const float*)d_in[18];

    const int H = 128;
    const int N = in_sizes[0] / H;   // 32768
    const int E = in_sizes[5];       // 262144
    const int SLOT1 = E / 2 + 4096;  // 135168, %128==0
    (void)n_in; (void)out_size;

    // ---- workspace layout ----
    char* ws = (char*)d_ws;
    size_t o = 0;
    auto take = [&](size_t b) { char* p = ws + o; o += (b + 255) & ~(size_t)255; return p; };
    bf16*  xb     = (bf16*)take((size_t)N * 384 * 2);        // 25.2 MB [P1..P3]
    bf16*  mub    = (bf16*)take((size_t)N * 384 * 2);        // 25.2 MB [P3]
    bf16*  filc   = (bf16*)take((size_t)SLOT1 * 384 * 2);    // 103.8 MB [P3]
    bf16*  hf     = (bf16*)take((size_t)SLOT1 * 128 * 2);    // 34.6 MB (unused)
    int*   perm   = (int*)take((size_t)2 * SLOT1 * 4);
    int*   srcp   = (int*)take((size_t)2 * SLOT1 * 4);
    float* cutp   = (float*)take((size_t)2 * SLOT1 * 4);
    float* uvp    = (float*)take((size_t)2 * SLOT1 * 12);
    int*   hist   = (int*)take((size_t)N * 4);
    int*   off    = (int*)take((size_t)(N + 64) * 4);
    int*   cursor = (int*)take((size_t)N * 4);
    bf16*  wts    = (bf16*)take(1100000);
    if (o > ws_size) return;
    (void)hf;
    // P5 aliases (xb/mub/filc dead): 134.3 MB < 188.8 MB transient region
    bf16*  mcat  = (bf16*)ws;
    bf16*  scin  = mcat + (size_t)N * 768;
    float* inner = (float*)(scin + (size_t)N * 256);
    bf16*  s1    = (bf16*)(inner + (size_t)N * 128);
    bf16*  delta = s1 + (size_t)N * 384;

    bf16* Wi1t = wts;             // [384][128]
    bf16* Wi2t = Wi1t + 49152;    // [384][384]
    bf16* Wf1t = Wi2t + 147456;   // [128][32]
    bf16* Wf2t = Wf1t + 4096;     // [384][128]
    bf16* Wvt  = Wf2t + 49152;    // [256][128]
    bf16* Ws1t = Wvt  + 32768;    // [384][256]
    bf16* Ws2t = Ws1t + 98304;    // [384][384]

    float* outq  = (float*)d_out;
    float* outmu = outq + (size_t)N * 128;

    dim3 blk(256);

    // ---- P0: weights -> bf16 transposed; mu -> bf16 ----
    {
        CvtArgs a;
        const float* wi[7] = {Wi1, Wi2, Wf1, Wf2, Wv, Ws1, Ws2};
        bf16* wo[7] = {Wi1t, Wi2t, Wf1t, Wf2t, Wvt, Ws1t, Ws2t};
        int K[7]  = {128, 384, 20, 128, 128, 256, 384};
        int Nc[7] = {384, 384, 128, 384, 256, 384, 384};
        int Kp[7] = {128, 384, 32, 128, 128, 256, 384};
        int c = 0;
        for (int s = 0; s < 7; ++s) {
            a.in[s] = wi[s]; a.out[s] = wo[s];
            a.K[s] = K[s]; a.Nc[s] = Nc[s]; a.Kp[s] = Kp[s];
            a.cum[s] = c; c += Nc[s] * Kp[s];
        }
        a.cum[7] = c;
        cvt_all<<<dim3((c + 255) / 256), blk, 0, stream>>>(a);
        cvt_bf16<<<dim3((unsigned)((size_t)N * 384 / 4 / 256)), blk, 0, stream>>>(
            (const float4*)mu, mub, (size_t)N * 384 / 4);
    }

    // ---- P1: interaction MLP (full) ----
    {
        bf16* x1 = filc;   // scratch
        mgemm<float, bf16, 1><<<dim3(N / 128, 3), blk, 0, stream>>>(
            q, Wi1t, bi1, nullptr, x1, N, 128, 384, 128);
        mgemm<bf16, bf16, 0><<<dim3(N / 128, 3), blk, 0, stream>>>(
            x1, Wi2t, bi2, nullptr, xb, N, 384, 384, 0);
    }

    // ---- PS: counting sort by target ----
    zero_k<<<dim3((N / 4 + 255) / 256), blk, 0, stream>>>((float4*)hist, N / 4);
    hist_k<<<dim3(E / 256), blk, 0, stream>>>(ei, hist, E);
    scan_k<<<dim3(1), blk, 0, stream>>>(hist, off, cursor, N, SLOT1);
    scatter_k<<<dim3(E / 256), blk, 0, stream>>>(ei, uv, cut, cursor,
                                                 perm, srcp, cutp, uvp, E);

    // ---- P3: fused filter pipeline + segmented edge reduce, 2 chunks ----
    for (int c = 0; c < 2; ++c) {
        int base = c * SLOT1;
        fil_fused<<<dim3(SLOT1 / 128), blk, 0, stream>>>(
            rbf, Wf1t, bf1, Wf2t, bf2, cutp + base, perm + base, filc,
            (unsigned)(E - 1));
        edge_seg<<<dim3(16384 / 4), blk, 0, stream>>>(
            xb, filc, mub, srcp, uvp, off, hist, q, mu, outq, outmu,
            c * 16384, 16384, base);
    }

    // ---- P5: mixing (full) ----
    mgemm<float, bf16, 0><<<dim3(3 * N / 128, 2), blk, 0, stream>>>(
        outmu, Wvt, nullptr, nullptr, mcat, 3 * N, 128, 256, 128);
    mix_pre<<<dim3(N * 64 / 256), blk, 0, stream>>>(mcat, outq, scin, inner, N);
    mgemm<bf16, bf16, 1><<<dim3(N / 128, 3), blk, 0, stream>>>(
        scin, Ws1t, bs1, nullptr, s1, N, 256, 384, 0);
    mgemm<bf16, bf16, 0><<<dim3(N / 128, 3), blk, 0, stream>>>(
        s1, Ws2t, bs2, nullptr, delta, N, 384, 384, 0);
    mix_post<<<dim3(N * 64 / 256), blk, 0, stream>>>(delta, inner, mcat,
                                                     outq, outmu, N);
}